// Round 7
// baseline (262.006 us; speedup 1.0000x reference)
//
#include <hip/hip_runtime.h>

typedef __attribute__((ext_vector_type(8))) short short8;
typedef __attribute__((ext_vector_type(4))) float floatx4;

// ws layout (ushort element offsets):
static constexpr size_t QOFF = 0;           // Q bf16 scaled [256][512][64]
static constexpr size_t KOFF = 8388608;     // K bf16 [256][512][64]
static constexpr size_t VTOFF = 16777216;   // V^T bf16 [256][64][512]
static constexpr size_t RBOFF = 25165824;   // rel bf16 [1025][64]
static constexpr size_t XBOFF = 25231424;   // X bf16 [16384][512]
static constexpr size_t WTOFF = 33620032;   // Wqkv^T bf16 [1536][512]
static constexpr size_t WOTOFF = 34406464;  // Wout^T bf16 [512][512]
static constexpr size_t OBOFF = 34668608;   // O bf16 [16384][512]

__device__ inline unsigned short f2b(float f) {  // round-half-up fp32->bf16 (2 VALU)
  return (unsigned short)((__float_as_uint(f) + 0x8000u) >> 16);
}
__device__ inline float b2f(unsigned short h) {
  return __uint_as_float(((unsigned int)h) << 16);
}
// pack two bf16 (round-half-up): returns (bf16(hi)<<16)|bf16(lo) in 3 VALU
__device__ inline unsigned int pk2(float hi, float lo) {
  return __builtin_amdgcn_perm(__float_as_uint(hi) + 0x8000u,
                               __float_as_uint(lo) + 0x8000u, 0x07060302u);
}

// ---------------------------------------------------------------------------
// Kernel 0: merged prep — x_cvt | Wqkv^T cvt | Wout^T cvt | rel cvt
// ---------------------------------------------------------------------------
__global__ __launch_bounds__(256) void prep(const float* __restrict__ x,
                                            const float* __restrict__ Wqkv,
                                            const float* __restrict__ Wout,
                                            const float* __restrict__ rel,
                                            unsigned short* __restrict__ wsb) {
  __shared__ float T[64 * 65];
  const int bx = blockIdx.x;
  const int tid = threadIdx.x;
  if (bx < 4096) {  // x -> bf16
    size_t i8 = ((size_t)bx * 256 + tid) * 8;
    float4 a = *(const float4*)(x + i8);
    float4 b = *(const float4*)(x + i8 + 4);
    uint4 o = {pk2(a.y, a.x), pk2(a.w, a.z), pk2(b.y, b.x), pk2(b.w, b.z)};
    *(uint4*)(wsb + XBOFF + i8) = o;
  } else if (bx < 4352) {  // transpose+convert
    const bool isq = bx < 4288;
    const int z = isq ? bx - 4096 : bx - 4288;
    const int C = isq ? 1536 : 512;
    const int R = 512;
    const int c0 = (isq ? (z % 24) : (z % 8)) * 64;
    const int r0 = (isq ? (z / 24) : (z / 8)) * 64;
    const float* in = isq ? Wqkv : Wout;
    unsigned short* out = wsb + (isq ? WTOFF : WOTOFF);
#pragma unroll
    for (int p = 0; p < 4; ++p) {
      int r = (tid >> 4) + p * 16, c4 = (tid & 15) * 4;
      float4 v = *(const float4*)(in + (size_t)(r0 + r) * C + c0 + c4);
      T[r * 65 + c4 + 0] = v.x;
      T[r * 65 + c4 + 1] = v.y;
      T[r * 65 + c4 + 2] = v.z;
      T[r * 65 + c4 + 3] = v.w;
    }
    __syncthreads();
#pragma unroll
    for (int p = 0; p < 4; ++p) {
      int oc = (tid >> 4) + p * 16;
      int or4 = (tid & 15) * 4;
      uint2 o = {pk2(T[(or4 + 1) * 65 + oc], T[(or4 + 0) * 65 + oc]),
                 pk2(T[(or4 + 3) * 65 + oc], T[(or4 + 2) * 65 + oc])};
      *(uint2*)(out + (size_t)(c0 + oc) * R + r0 + or4) = o;
    }
  } else {  // rel -> bf16
    int i = (bx - 4352) * 256 + tid;
    if (i < 65600) wsb[RBOFF + i] = f2b(rel[i]);
  }
}

// ---------------------------------------------------------------------------
// Kernel 1: qkv = Xb @ Wt^T (bf16 MFMA) with register-prefetch pipeline.
// ---------------------------------------------------------------------------
__global__ __launch_bounds__(256) void qkv_mfma(const unsigned short* __restrict__ Xb,
                                                const unsigned short* __restrict__ Wt,
                                                unsigned short* __restrict__ wsb) {
  __shared__ __align__(16) unsigned short As[128 * 40];
  __shared__ __align__(16) unsigned short Bs[128 * 40];
  const int tid = threadIdx.x;
  const int w = tid >> 6, lane = tid & 63;
  const int g = lane >> 4, c = lane & 15;
  const int m0 = blockIdx.x * 128, n0 = blockIdx.y * 128;
  const int wr = (w >> 1) * 64, wc = (w & 1) * 64;
  const bool vmode = (blockIdx.y >= 8);

  const int rA = tid >> 2, oA = tid & 3;

  floatx4 acc[4][4];
#pragma unroll
  for (int mi = 0; mi < 4; ++mi)
#pragma unroll
    for (int ni = 0; ni < 4; ++ni) acc[mi][ni] = (floatx4){0.f, 0.f, 0.f, 0.f};

  uint4 pa0 = *(const uint4*)(Xb + (size_t)(m0 + rA) * 512 + oA * 8);
  uint4 pa1 = *(const uint4*)(Xb + (size_t)(m0 + rA + 64) * 512 + oA * 8);
  uint4 pb0 = *(const uint4*)(Wt + (size_t)(n0 + rA) * 512 + oA * 8);
  uint4 pb1 = *(const uint4*)(Wt + (size_t)(n0 + rA + 64) * 512 + oA * 8);

  for (int kk = 0; kk < 512; kk += 32) {
    __syncthreads();
    *(uint4*)(As + rA * 40 + oA * 8) = pa0;
    *(uint4*)(As + (rA + 64) * 40 + oA * 8) = pa1;
    *(uint4*)(Bs + rA * 40 + oA * 8) = pb0;
    *(uint4*)(Bs + (rA + 64) * 40 + oA * 8) = pb1;
    __syncthreads();
    const int kkn = (kk < 480) ? kk + 32 : kk;
    pa0 = *(const uint4*)(Xb + (size_t)(m0 + rA) * 512 + kkn + oA * 8);
    pa1 = *(const uint4*)(Xb + (size_t)(m0 + rA + 64) * 512 + kkn + oA * 8);
    pb0 = *(const uint4*)(Wt + (size_t)(n0 + rA) * 512 + kkn + oA * 8);
    pb1 = *(const uint4*)(Wt + (size_t)(n0 + rA + 64) * 512 + kkn + oA * 8);

    short8 a[4], b[4];
#pragma unroll
    for (int mi = 0; mi < 4; ++mi) a[mi] = *(const short8*)(As + (wr + mi * 16 + c) * 40 + g * 8);
#pragma unroll
    for (int ni = 0; ni < 4; ++ni) b[ni] = *(const short8*)(Bs + (wc + ni * 16 + c) * 40 + g * 8);
    if (vmode) {
#pragma unroll
      for (int mi = 0; mi < 4; ++mi)
#pragma unroll
        for (int ni = 0; ni < 4; ++ni)
          acc[mi][ni] = __builtin_amdgcn_mfma_f32_16x16x32_bf16(b[ni], a[mi], acc[mi][ni], 0, 0, 0);
    } else {
#pragma unroll
      for (int mi = 0; mi < 4; ++mi)
#pragma unroll
        for (int ni = 0; ni < 4; ++ni)
          acc[mi][ni] = __builtin_amdgcn_mfma_f32_16x16x32_bf16(a[mi], b[ni], acc[mi][ni], 0, 0, 0);
    }
  }

  constexpr float SCL = 0.125f * 1.44269504088896340736f;
  if (vmode) {
#pragma unroll
    for (int mi = 0; mi < 4; ++mi) {
      const int xrow = m0 + wr + mi * 16 + c;
      const int bb = xrow >> 9, nn = xrow & 511;
#pragma unroll
      for (int ni = 0; ni < 4; ++ni) {
#pragma unroll
        for (int r = 0; r < 4; ++r) {
          const int C = n0 + wc + ni * 16 + g * 4 + r;
          const int col512 = C & 511;
          const int h = col512 >> 6, d = col512 & 63;
          wsb[VTOFF + (size_t)(bb * 8 + h) * 32768 + (size_t)d * 512 + nn] = f2b(acc[mi][ni][r]);
        }
      }
    }
  } else {
    const size_t base = (blockIdx.y >= 4) ? KOFF : QOFF;
    const float scl = (blockIdx.y >= 4) ? 1.0f : SCL;
#pragma unroll
    for (int ni = 0; ni < 4; ++ni) {
      const int C = n0 + wc + ni * 16 + c;
      const int col512 = C & 511;
      const int h = col512 >> 6, d = col512 & 63;
#pragma unroll
      for (int mi = 0; mi < 4; ++mi) {
#pragma unroll
        for (int r = 0; r < 4; ++r) {
          const int xrow = m0 + wr + mi * 16 + g * 4 + r;
          wsb[base + (size_t)((xrow >> 9) * 8 + h) * 32768 + (size_t)(xrow & 511) * 64 + d] =
              f2b(acc[mi][ni][r] * scl);
        }
      }
    }
  }
}

// ---------------------------------------------------------------------------
// Kernel 2: MFMA flash attention, software-pipelined, Ps aliased onto Gs.
// LDS 29.7 KB -> 5 blocks/CU. Grid (bh, i-tile) so one bh sticks to one XCD.
// ---------------------------------------------------------------------------
__global__ __launch_bounds__(256) void attn_mfma(const unsigned short* __restrict__ wsb,
                                                 unsigned short* __restrict__ Ob) {
  __shared__ __align__(16) unsigned short Ks[64 * 72];
  __shared__ __align__(16) unsigned short Vt[64 * 72];
  // per-wave union: rows [i=16] x 88; Gs occupies cols [0,80) (fp-bf16 bias),
  // Ps overlays cols [0,64) AFTER the gather reads complete (wave-private).
  __shared__ __align__(16) unsigned short U[4 * 16 * 88];

  const int tid = threadIdx.x;
  const int w = tid >> 6, lane = tid & 63;
  const int g = lane >> 4, c = lane & 15;
  const int bh = blockIdx.x, i0 = blockIdx.y * 64;

  const unsigned short* Qg = wsb + QOFF + (size_t)bh * 32768 + (size_t)i0 * 64;
  const unsigned short* Kg = wsb + KOFF + (size_t)bh * 32768;
  const unsigned short* Vg = wsb + VTOFF + (size_t)bh * 32768;
  const unsigned short* Rg = wsb + RBOFF;

  const short8 bq0 = *(const short8*)(Qg + (size_t)(w * 16 + c) * 64 + g * 8);
  const short8 bq1 = *(const short8*)(Qg + (size_t)(w * 16 + c) * 64 + 32 + g * 8);

  unsigned short* UW = U + w * (16 * 88);
  unsigned short* RowW = UW + c * 88;  // this lane's i-row (Gs and Ps share it)

  const int r0s = tid >> 3, o0s = tid & 7;
  const int r1s = r0s + 32;

  uint4 pk0 = *(const uint4*)(Kg + (size_t)r0s * 64 + o0s * 8);
  uint4 pk1 = *(const uint4*)(Kg + (size_t)r1s * 64 + o0s * 8);
  uint4 pv0 = *(const uint4*)(Vg + (size_t)r0s * 512 + o0s * 8);
  uint4 pv1 = *(const uint4*)(Vg + (size_t)r1s * 512 + o0s * 8);

  float m_i = -1e30f, l_i = 0.f;
  floatx4 oa[4];
#pragma unroll
  for (int t = 0; t < 4; ++t) oa[t] = (floatx4){0.f, 0.f, 0.f, 0.f};

  for (int jc = 0; jc < 8; ++jc) {
    const int j0 = jc * 64;
    __syncthreads();
    *(uint4*)(Ks + r0s * 72 + o0s * 8) = pk0;
    *(uint4*)(Ks + r1s * 72 + o0s * 8) = pk1;
    *(uint4*)(Vt + r0s * 72 + o0s * 8) = pv0;
    *(uint4*)(Vt + r1s * 72 + o0s * 8) = pv1;
    __syncthreads();

    // T loads for this chunk (latency hides behind S phase)
    const int dbase = i0 - j0 + 449 + w * 16;
    const unsigned short* Trow = Rg + (size_t)(dbase + c) * 64;
    short8 t0[5], t1[5];
#pragma unroll
    for (int dd = 0; dd < 5; ++dd) {
      t0[dd] = *(const short8*)(Trow + dd * 1024 + g * 8);
      t1[dd] = *(const short8*)(Trow + dd * 1024 + 32 + g * 8);
    }
    // prefetch next chunk's K/V
    const int j0n = (jc < 7) ? j0 + 64 : j0;
    pk0 = *(const uint4*)(Kg + (size_t)(j0n + r0s) * 64 + o0s * 8);
    pk1 = *(const uint4*)(Kg + (size_t)(j0n + r1s) * 64 + o0s * 8);
    pv0 = *(const uint4*)(Vg + (size_t)r0s * 512 + j0n + o0s * 8);
    pv1 = *(const uint4*)(Vg + (size_t)r1s * 512 + j0n + o0s * 8);

    // S' = K @ Q^T : D[m=j][n=i]; lane (g,c): j = 16t+4g+r, i = c
    floatx4 s4[4];
#pragma unroll
    for (int t = 0; t < 4; ++t) {
      short8 k0 = *(const short8*)(Ks + (t * 16 + c) * 72 + g * 8);
      short8 k1 = *(const short8*)(Ks + (t * 16 + c) * 72 + 32 + g * 8);
      floatx4 sa = (floatx4){0.f, 0.f, 0.f, 0.f};
      sa = __builtin_amdgcn_mfma_f32_16x16x32_bf16(k0, bq0, sa, 0, 0, 0);
      sa = __builtin_amdgcn_mfma_f32_16x16x32_bf16(k1, bq1, sa, 0, 0, 0);
      s4[t] = sa;
    }

    // G' = rel-window @ Q^T -> Gs bf16 [i=c][delta' in [0,80)]
#pragma unroll
    for (int dd = 0; dd < 5; ++dd) {
      floatx4 ga = (floatx4){0.f, 0.f, 0.f, 0.f};
      ga = __builtin_amdgcn_mfma_f32_16x16x32_bf16(t0[dd], bq0, ga, 0, 0, 0);
      ga = __builtin_amdgcn_mfma_f32_16x16x32_bf16(t1[dd], bq1, ga, 0, 0, 0);
      uint2 gk = {pk2(ga[1], ga[0]), pk2(ga[3], ga[2])};
      *(uint2*)(RowW + dd * 16 + 4 * g) = gk;
    }

    // Toeplitz bias gather: delta' = c - jloc + 63 in [0,79]
    const unsigned short* Grow = RowW + c + 63;
#pragma unroll
    for (int t = 0; t < 4; ++t)
#pragma unroll
      for (int r = 0; r < 4; ++r) s4[t][r] += b2f(Grow[-(16 * t + 4 * g + r)]);

    // online softmax (base-2): one row (i = c) per lane, replicated over g
    float mx = -1e30f;
#pragma unroll
    for (int t = 0; t < 4; ++t)
      mx = fmaxf(mx, fmaxf(fmaxf(s4[t][0], s4[t][1]), fmaxf(s4[t][2], s4[t][3])));
    mx = fmaxf(mx, __shfl_xor(mx, 16));
    mx = fmaxf(mx, __shfl_xor(mx, 32));
    const float mn = fmaxf(m_i, mx);
    const float al = exp2f(m_i - mn);
    m_i = mn;
    float ls = 0.f;
#pragma unroll
    for (int t = 0; t < 4; ++t)
#pragma unroll
      for (int r = 0; r < 4; ++r) {
        float p = exp2f(s4[t][r] - mn);
        s4[t][r] = p;
        ls += p;
      }
    ls += __shfl_xor(ls, 16);
    ls += __shfl_xor(ls, 32);
    l_i = l_i * al + ls;

#pragma unroll
    for (int r = 0; r < 4; ++r) {
      const float ar = __shfl(al, 4 * g + r);
#pragma unroll
      for (int dt = 0; dt < 4; ++dt) oa[dt][r] *= ar;
    }

    // P store overlays Gs row (gather reads above are done): [i=c][j], b64
#pragma unroll
    for (int t = 0; t < 4; ++t) {
      uint2 pk = {pk2(s4[t][1], s4[t][0]), pk2(s4[t][3], s4[t][2])};
      *(uint2*)(RowW + t * 16 + 4 * g) = pk;
    }

    // PV: A = P[i=c][j], B = V^T[d][j]
    short8 ap0 = *(const short8*)(RowW + g * 8);
    short8 ap1 = *(const short8*)(RowW + 32 + g * 8);
#pragma unroll
    for (int dt = 0; dt < 4; ++dt) {
      short8 bv0 = *(const short8*)(Vt + (dt * 16 + c) * 72 + g * 8);
      short8 bv1 = *(const short8*)(Vt + (dt * 16 + c) * 72 + 32 + g * 8);
      oa[dt] = __builtin_amdgcn_mfma_f32_16x16x32_bf16(ap0, bv0, oa[dt], 0, 0, 0);
      oa[dt] = __builtin_amdgcn_mfma_f32_16x16x32_bf16(ap1, bv1, oa[dt], 0, 0, 0);
    }
  }

  const int b = bh >> 3, h = bh & 7;
  const float invl = 1.0f / l_i;
#pragma unroll
  for (int r = 0; r < 4; ++r) {
    const float inv = __shfl(invl, 4 * g + r);
    const int i = i0 + w * 16 + 4 * g + r;
    const size_t rowoff = ((size_t)(b * 512 + i)) * 512 + h * 64;
#pragma unroll
    for (int dt = 0; dt < 4; ++dt) Ob[rowoff + dt * 16 + c] = f2b(oa[dt][r] * inv);
  }
}

// ---------------------------------------------------------------------------
// Kernel 3: out = Ob[16384x512] @ WoT^T + bias (bf16 MFMA, fp32 out),
// register-prefetch pipeline.
// ---------------------------------------------------------------------------
__global__ __launch_bounds__(256) void out_mfma(const unsigned short* __restrict__ Ab,
                                                const unsigned short* __restrict__ Bt,
                                                const float* __restrict__ bias,
                                                float* __restrict__ out) {
  __shared__ __align__(16) unsigned short As[128 * 40];
  __shared__ __align__(16) unsigned short Bs[128 * 40];
  const int tid = threadIdx.x;
  const int w = tid >> 6, lane = tid & 63;
  const int g = lane >> 4, c = lane & 15;
  const int m0 = blockIdx.x * 128, n0 = blockIdx.y * 128;
  const int wr = (w >> 1) * 64, wc = (w & 1) * 64;

  const int rA = tid >> 2, oA = tid & 3;

  floatx4 acc[4][4];
#pragma unroll
  for (int mi = 0; mi < 4; ++mi)
#pragma unroll
    for (int ni = 0; ni < 4; ++ni) acc[mi][ni] = (floatx4){0.f, 0.f, 0.f, 0.f};

  uint4 pa0 = *(const uint4*)(Ab + (size_t)(m0 + rA) * 512 + oA * 8);
  uint4 pa1 = *(const uint4*)(Ab + (size_t)(m0 + rA + 64) * 512 + oA * 8);
  uint4 pb0 = *(const uint4*)(Bt + (size_t)(n0 + rA) * 512 + oA * 8);
  uint4 pb1 = *(const uint4*)(Bt + (size_t)(n0 + rA + 64) * 512 + oA * 8);

  for (int kk = 0; kk < 512; kk += 32) {
    __syncthreads();
    *(uint4*)(As + rA * 40 + oA * 8) = pa0;
    *(uint4*)(As + (rA + 64) * 40 + oA * 8) = pa1;
    *(uint4*)(Bs + rA * 40 + oA * 8) = pb0;
    *(uint4*)(Bs + (rA + 64) * 40 + oA * 8) = pb1;
    __syncthreads();
    const int kkn = (kk < 480) ? kk + 32 : kk;
    pa0 = *(const uint4*)(Ab + (size_t)(m0 + rA) * 512 + kkn + oA * 8);
    pa1 = *(const uint4*)(Ab + (size_t)(m0 + rA + 64) * 512 + kkn + oA * 8);
    pb0 = *(const uint4*)(Bt + (size_t)(n0 + rA) * 512 + kkn + oA * 8);
    pb1 = *(const uint4*)(Bt + (size_t)(n0 + rA + 64) * 512 + kkn + oA * 8);

    short8 a[4], b[4];
#pragma unroll
    for (int mi = 0; mi < 4; ++mi) a[mi] = *(const short8*)(As + (wr + mi * 16 + c) * 40 + g * 8);
#pragma unroll
    for (int ni = 0; ni < 4; ++ni) b[ni] = *(const short8*)(Bs + (wc + ni * 16 + c) * 40 + g * 8);
#pragma unroll
    for (int mi = 0; mi < 4; ++mi)
#pragma unroll
      for (int ni = 0; ni < 4; ++ni)
        acc[mi][ni] = __builtin_amdgcn_mfma_f32_16x16x32_bf16(a[mi], b[ni], acc[mi][ni], 0, 0, 0);
  }

#pragma unroll
  for (int ni = 0; ni < 4; ++ni) {
    const int C = n0 + wc + ni * 16 + c;
    const float bv = bias[C];
#pragma unroll
    for (int mi = 0; mi < 4; ++mi) {
#pragma unroll
      for (int r = 0; r < 4; ++r) {
        const int m = m0 + wr + mi * 16 + g * 4 + r;
        out[(size_t)m * 512 + C] = acc[mi][ni][r] + bv;
      }
    }
  }
}

// ---------------------------------------------------------------------------
extern "C" void kernel_launch(void* const* d_in, const int* in_sizes, int n_in,
                              void* d_out, int out_size, void* d_ws, size_t ws_size,
                              hipStream_t stream) {
  const float* x = (const float*)d_in[0];      // [32,512,512]
  const float* Wqkv = (const float*)d_in[1];   // [512,1536]
  const float* rel = (const float*)d_in[2];    // [1025,64]
  const float* Wout = (const float*)d_in[3];   // [512,512]
  const float* bout = (const float*)d_in[4];   // [512]
  float* out = (float*)d_out;
  unsigned short* wsb = (unsigned short*)d_ws;

  prep<<<4609, 256, 0, stream>>>(x, Wqkv, Wout, rel, wsb);
  qkv_mfma<<<dim3(128, 12), 256, 0, stream>>>(wsb + XBOFF, wsb + WTOFF, wsb);
  attn_mfma<<<dim3(256, 8), 256, 0, stream>>>(wsb, wsb + OBOFF);
  out_mfma<<<dim3(128, 4), 256, 0, stream>>>(wsb + OBOFF, wsb + WOTOFF, bout, out);
}